// Round 3
// baseline (236.643 us; speedup 1.0000x reference)
//
#include <hip/hip_runtime.h>
#include <cstdint>
#include <cstddef>

#define NIMG 256
#define PADW 18
#define XB_IMG (PADW * PADW * 256)   // 82944 elements per image
#define W2_ROW 2304                  // 9*256

typedef __bf16 bf16x8 __attribute__((ext_vector_type(8)));
typedef float floatx4 __attribute__((ext_vector_type(4)));
typedef float floatx16 __attribute__((ext_vector_type(16)));
typedef float floatvec4 __attribute__((ext_vector_type(4)));

__device__ __forceinline__ unsigned short f2bf(float f) {
    unsigned u = __float_as_uint(f);
    u = (u + 0x7FFFu + ((u >> 16) & 1u)) >> 16;   // RNE
    return (unsigned short)u;
}

__device__ __forceinline__ void gload_lds16(const void* g, void* l) {
    __builtin_amdgcn_global_load_lds(
        (const __attribute__((address_space(1))) void*)g,
        (__attribute__((address_space(3))) void*)l, 16, 0, 0);
}

// ---------------------------------------------------------------------------
// Kernel 1 v2: x NCHW fp32 -> xb[n][py][px][c] bf16, padded 18x18, halo zeroed.
// float4 global reads (16 instr/thread vs 64 scalar), packed b64 LDS writes.
// tile2[c][p] with pitch 268 shorts (134 dwords == 6 mod 32 -> 2-way reads).
// grid (256 images, 4 c-groups of 64), block 256.
// ---------------------------------------------------------------------------
__global__ __launch_bounds__(256) void convert_kernel(
        const float* __restrict__ x, unsigned short* __restrict__ xb) {
    __shared__ __align__(16) unsigned short tile2[64][268];
    const int n  = blockIdx.x;
    const int c0 = blockIdx.y * 64;
    const int t  = threadIdx.x;
    const float* xi = x + (size_t)n * 65536;
    unsigned short* xo = xb + (size_t)n * XB_IMG;

    // halo zero (68 border pixels * 256 ch), 8B stores, by c-group 0 only
    if (blockIdx.y == 0) {
        #pragma unroll
        for (int it = 0; it < 17; ++it) {
            int idx = it * 256 + t;          // 0..4351 = 68*64
            int hp = idx >> 6;
            int c4 = (idx & 63) * 4;
            int py, px;
            if (hp < 18)      { py = 0;       px = hp;      }
            else if (hp < 36) { py = 17;      px = hp - 18; }
            else if (hp < 52) { py = hp - 35; px = 0;       }
            else              { py = hp - 51; px = 17;      }
            *(uint2*)&xo[(py * 18 + px) * 256 + c4] = make_uint2(0u, 0u);
        }
    }

    // phase 1: vectorized load + convert + pack -> LDS [c][p]
    {
        const int p4 = (t & 63) * 4;
        const int ci = t >> 6;               // 0..3 within each 4-ch pass
        #pragma unroll
        for (int i = 0; i < 16; ++i) {
            const int c = i * 4 + ci;        // local channel 0..63
            floatvec4 v = *(const floatvec4*)&xi[(c0 + c) * 256 + p4];
            unsigned lo = (unsigned)f2bf(v.x) | ((unsigned)f2bf(v.y) << 16);
            unsigned hi = (unsigned)f2bf(v.z) | ((unsigned)f2bf(v.w) << 16);
            *(uint2*)&tile2[c][p4] = make_uint2(lo, hi);
        }
    }
    __syncthreads();

    // phase 2: per pixel, 64 contiguous bf16 channels (pack pairs from rows)
    #pragma unroll
    for (int it = 0; it < 32; ++it) {
        int idx = it * 256 + t;
        int p   = idx >> 5;                  // pixel 0..255
        int cp  = (idx & 31) * 2;            // channel pair 0..62
        unsigned lo = tile2[cp][p];
        unsigned hi = tile2[cp + 1][p];
        int py = (p >> 4) + 1, px = (p & 15) + 1;
        *(unsigned int*)&xo[(py * 18 + px) * 256 + c0 + cp] = lo | (hi << 16);
    }
}

// ---------------------------------------------------------------------------
// Kernel 2: combined circulant weight w2[kout][pos][c] bf16. (unchanged)
// ---------------------------------------------------------------------------
__global__ __launch_bounds__(256) void wprep_kernel(
        const float* __restrict__ wt, const float* __restrict__ alphas,
        unsigned short* __restrict__ w2) {
    __shared__ float wlds[16][257];
    const int o16 = blockIdx.x * 16;
    const int pos = blockIdx.y;
    const int t   = threadIdx.x;

    #pragma unroll
    for (int j = 0; j < 16; ++j)
        wlds[j][t] = wt[((o16 + j) * 256 + t) * 9 + pos];

    float a[5];
    {
        float mx = alphas[0];
        #pragma unroll
        for (int i = 1; i < 5; ++i) mx = fmaxf(mx, alphas[i]);
        float s = 0.f;
        #pragma unroll
        for (int i = 0; i < 5; ++i) { a[i] = __expf(alphas[i] - mx); s += a[i]; }
        float inv = 1.f / s;
        #pragma unroll
        for (int i = 0; i < 5; ++i) a[i] *= inv;
    }
    __syncthreads();

    const int c = t;
    #pragma unroll
    for (int oo = 0; oo < 16; ++oo) {
        float acc = a[0] * wlds[oo][c];
        #pragma unroll
        for (int bi = 0; bi < 4; ++bi) {
            const int b  = 2 << bi;            // 2,4,8,16
            const int r  = oo & (b - 1);
            const int cc = c & (b - 1);
            const int i0 = (r - cc) & (b - 1);
            const int ob = oo - r;
            const int icb = c - cc;
            float s2 = 0.f;
            for (int j = 0; j < b; ++j)
                s2 += wlds[ob + j][icb + ((j + i0) & (b - 1))];
            acc += a[1 + bi] * s2 * (1.f / (float)b);
        }
        w2[(size_t)(o16 + oo) * W2_ROW + pos * 256 + c] = f2bf(acc);
    }
}

// ---------------------------------------------------------------------------
// Kernel 3 v3: implicit-GEMM conv, 32x32x16 MFMA (4064 FLOP/cyc vs 3379 for
// 16x16x32; half the MFMA issue slots). 128x128 block tile, BK=64, same
// XOR-swizzled global_load_lds staging + XCD-paired grid as v2.
// Wave = 64x64 = 2x2 tiles of 32x32. A-frag: m=lane&31, k=(lane>>5)*8+j.
// C/D: col=lane&31, row=(reg&3)+8*(reg>>2)+4*(lane>>5)  [m74/m101 verified].
// ---------------------------------------------------------------------------
__global__ __launch_bounds__(256) void gemm_kernel(
        const unsigned short* __restrict__ xb,
        const unsigned short* __restrict__ w2,
        float* __restrict__ out) {
    __shared__ __align__(16) unsigned short xs[128 * 64];  // [pixel][64ch] 16 KB
    __shared__ __align__(16) unsigned short ws[128 * 64];  // [kout ][64ch] 16 KB

    const int t    = threadIdx.x;
    const int lane = t & 63;
    const int wid  = t >> 6;

    // XCD-paired decode: b&7 = XCD slot; both ktiles of a ptile share it.
    const int b     = blockIdx.x;
    const int s_    = b >> 3;                   // 0..127
    const int ptile = (b & 7) * 64 + (s_ >> 1); // 0..511
    const int ktile = s_ & 1;
    const int n_img = ptile >> 1;
    const int half  = ptile & 1;
    const int kbase = ktile * 128;

    // ---- staging: waves 0/1 -> xs, waves 2/3 -> ws; 8 rows per instr
    const int rlo  = lane >> 3;                        // row within 8-row chunk
    const int cswz = ((lane & 7) - rlo) & 7;           // swizzled ch-group
    const int coff = cswz * 8;

    int xg[8], wg[8];
    {
        const int sub = wid & 1;
        #pragma unroll
        for (int i = 0; i < 8; ++i) {
            int r = sub * 64 + i * 8 + rlo;            // tile row 0..127
            int y  = half * 8 + (r >> 4);
            int xq = r & 15;
            xg[i] = n_img * XB_IMG + ((y + 1) * 18 + (xq + 1)) * 256 + coff;
            int kr = kbase + sub * 64 + i * 8 + rlo;
            wg[i] = kr * W2_ROW + coff;
        }
    }
    const int lds_base = (wid & 1) * 4096;

    floatx16 acc[2][2];
    #pragma unroll
    for (int i = 0; i < 2; ++i)
        #pragma unroll
        for (int j = 0; j < 2; ++j)
            #pragma unroll
            for (int r = 0; r < 16; ++r) acc[i][j][r] = 0.f;

    // ---- reader offsets (swizzled). m-tiles 32 apart share slot (32 % 8 == 0).
    const int wrow = wid >> 1, wcol = wid & 1;
    const int l31  = lane & 31, lhi = lane >> 5;
    const int ar   = wrow * 64 + l31;            // A row, tile_m=0 (tile_m=1: +32)
    const int br   = wcol * 64 + l31;            // B row
    const int sa0  = (ar + lhi) & 7;             // slot at ks=0
    const int sb0  = (br + lhi) & 7;

    for (int pos = 0; pos < 9; ++pos) {
        const int dp = ((pos / 3) - 1) * (18 * 256) + ((pos % 3) - 1) * 256;
        #pragma unroll
        for (int cs = 0; cs < 4; ++cs) {
            __syncthreads();
            if (wid < 2) {
                const int go = dp + cs * 64;
                #pragma unroll
                for (int i = 0; i < 8; ++i)
                    gload_lds16(xb + xg[i] + go, &xs[lds_base + i * 512]);
            } else {
                const int go = pos * 256 + cs * 64;
                #pragma unroll
                for (int i = 0; i < 8; ++i)
                    gload_lds16(w2 + wg[i] + go, &ws[lds_base + i * 512]);
            }
            __syncthreads();

            #pragma unroll
            for (int ks = 0; ks < 4; ++ks) {           // K=16 each
                const int sa = (sa0 + ks * 2) & 7;
                const int sb = (sb0 + ks * 2) & 7;
                bf16x8 af[2], bf[2];
                af[0] = *(const bf16x8*)&ws[ar * 64 + sa * 8];
                af[1] = *(const bf16x8*)&ws[(ar + 32) * 64 + sa * 8];
                bf[0] = *(const bf16x8*)&xs[br * 64 + sb * 8];
                bf[1] = *(const bf16x8*)&xs[(br + 32) * 64 + sb * 8];
                #pragma unroll
                for (int mt = 0; mt < 2; ++mt)
                    #pragma unroll
                    for (int nt = 0; nt < 2; ++nt)
                        acc[mt][nt] = __builtin_amdgcn_mfma_f32_32x32x16_bf16(
                            af[mt], bf[nt], acc[mt][nt], 0, 0, 0);
            }
        }
    }

    // epilogue: col=lane&31 -> pixel (coalesced), row=(r&3)+8*(r>>2)+4*lhi
    const int p0 = half * 128 + wcol * 64;
    const int k0 = kbase + wrow * 64;
    float* ob = out + (size_t)n_img * 65536;
    #pragma unroll
    for (int mt = 0; mt < 2; ++mt) {
        #pragma unroll
        for (int nt = 0; nt < 2; ++nt) {
            const int p = p0 + nt * 32 + l31;
            #pragma unroll
            for (int r = 0; r < 16; ++r) {
                const int kout = k0 + mt * 32 + (r & 3) + 8 * (r >> 2) + 4 * lhi;
                ob[kout * 256 + p] = acc[mt][nt][r];
            }
        }
    }
}

// ---------------------------------------------------------------------------
// Fallback (only if workspace too small for xb): naive conv using w2.
// ---------------------------------------------------------------------------
__global__ __launch_bounds__(256) void naive_conv(
        const float* __restrict__ x, const unsigned short* __restrict__ w2,
        float* __restrict__ out) {
    __shared__ float wr[2304];
    const int n = blockIdx.x >> 8, k = blockIdx.x & 255;
    const int t = threadIdx.x;
    for (int i = t; i < 2304; i += 256)
        wr[i] = __uint_as_float(((unsigned)w2[k * W2_ROW + i]) << 16);
    __syncthreads();
    const int y = t >> 4, xx = t & 15;
    const float* xi = x + (size_t)n * 65536;
    float acc = 0.f;
    for (int pos = 0; pos < 9; ++pos) {
        int dy = pos / 3 - 1, dx = pos % 3 - 1;
        int yy = y + dy, x2 = xx + dx;
        if (yy < 0 || yy > 15 || x2 < 0 || x2 > 15) continue;
        const float* xp = xi + yy * 16 + x2;
        const float* wp = wr + pos * 256;
        for (int c = 0; c < 256; ++c) acc += xp[c * 256] * wp[c];
    }
    out[(size_t)n * 65536 + k * 256 + t] = acc;
}

extern "C" void kernel_launch(void* const* d_in, const int* in_sizes, int n_in,
                              void* d_out, int out_size, void* d_ws, size_t ws_size,
                              hipStream_t stream) {
    const float* x      = (const float*)d_in[0];
    const float* wt     = (const float*)d_in[1];
    const float* alphas = (const float*)d_in[2];
    float* out = (float*)d_out;

    const size_t xb_elems = (size_t)NIMG * XB_IMG;          // 21,233,664
    const size_t w2_elems = (size_t)256 * W2_ROW;           //    589,824
    const size_t need = (xb_elems + w2_elems) * sizeof(unsigned short); // ~41.6 MB

    if (ws_size >= need) {
        unsigned short* xb = (unsigned short*)d_ws;
        unsigned short* w2 = xb + xb_elems;
        convert_kernel<<<dim3(256, 4), 256, 0, stream>>>(x, xb);
        wprep_kernel<<<dim3(16, 9), 256, 0, stream>>>(wt, alphas, w2);
        gemm_kernel<<<dim3(1024), 256, 0, stream>>>(xb, w2, out);
    } else if (ws_size >= w2_elems * sizeof(unsigned short)) {
        unsigned short* w2 = (unsigned short*)d_ws;
        wprep_kernel<<<dim3(16, 9), 256, 0, stream>>>(wt, alphas, w2);
        naive_conv<<<dim3(256 * 256), 256, 0, stream>>>(x, w2, out);
    }
}